// Round 1
// baseline (883.061 us; speedup 1.0000x reference)
//
#include <hip/hip_runtime.h>
#include <math.h>

#define D_MODEL 256
#define N_EXP   16
#define N_VIEWS 3
#define N_TOK   8192
#define TOPK    4
#define HDIM    1024
#define CH      64
#define NCH     16          // HDIM / CH
#define ROWS    128
#define NGROUP  48          // N_VIEWS * N_EXP
#define MAXTILE 64          // ceil(N_TOK / ROWS): a group holds <= N_TOK rows

typedef short s16x8 __attribute__((ext_vector_type(8)));
typedef float f32x4 __attribute__((ext_vector_type(4)));

__device__ __forceinline__ unsigned short f2bf(float x) {
    union { float f; unsigned u; } a; a.f = x;
    unsigned r = a.u + 0x7FFFu + ((a.u >> 16) & 1u);   // RNE
    return (unsigned short)(r >> 16);
}

// ------------------------------------------------------------------
// prep: cw[v][e][d] = 2*keys[e][d] + rw[v][e][d];  knorm[e] = ||k_e||^2
// ------------------------------------------------------------------
__global__ void prep_kernel(const float* __restrict__ rw, const float* __restrict__ keys,
                            float* __restrict__ cw, float* __restrict__ knorm) {
    int t = threadIdx.x;
    for (int i = t; i < N_VIEWS * N_EXP * D_MODEL; i += blockDim.x) {
        int ed = i % (N_EXP * D_MODEL);
        cw[i] = rw[i] + 2.0f * keys[ed];
    }
    if (t < N_EXP) {
        float s = 0.f;
        for (int d = 0; d < D_MODEL; d++) { float k = keys[t * D_MODEL + d]; s += k * k; }
        knorm[t] = s;
    }
}

// ------------------------------------------------------------------
// W1: [E][256][1024] f32  ->  W1s: [E][1024][256] bf16  (j-major = chunk-major)
// ------------------------------------------------------------------
__global__ void transpose_w1(const float* __restrict__ W1, unsigned short* __restrict__ W1s) {
    __shared__ float tile[64][65];
    int e  = blockIdx.z;
    int k0 = blockIdx.y * 64;   // 256/64 = 4
    int j0 = blockIdx.x * 64;   // 1024/64 = 16
    int tr = threadIdx.x / 64, tc = threadIdx.x % 64;
    #pragma unroll
    for (int i = 0; i < 16; i++) {
        int r = tr + i * 4;
        tile[r][tc] = W1[((size_t)e * 256 + (k0 + r)) * 1024 + j0 + tc];
    }
    __syncthreads();
    #pragma unroll
    for (int i = 0; i < 16; i++) {
        int r = tr + i * 4;
        W1s[((size_t)e * 1024 + (j0 + r)) * 256 + k0 + tc] = f2bf(tile[tc][r]);
    }
}

// ------------------------------------------------------------------
// W2: [E][1024][256] f32 -> W2s: [E][c(16)][n(256)][kk(64)] bf16,
//     W2s[e][c][n][kk] = W2[e][c*64+kk][n]
// ------------------------------------------------------------------
__global__ void transpose_w2(const float* __restrict__ W2, unsigned short* __restrict__ W2s) {
    __shared__ float tile[64][65];
    int e  = blockIdx.z;
    int c  = blockIdx.y;        // 16 k-slabs
    int n0 = blockIdx.x * 64;   // 256/64 = 4
    int tr = threadIdx.x / 64, tc = threadIdx.x % 64;
    #pragma unroll
    for (int i = 0; i < 16; i++) {
        int kk = tr + i * 4;
        tile[kk][tc] = W2[((size_t)e * 1024 + (c * 64 + kk)) * 256 + n0 + tc];
    }
    __syncthreads();
    #pragma unroll
    for (int i = 0; i < 16; i++) {
        int r = tr + i * 4;     // n_local
        W2s[(((size_t)e * NCH + c) * 256 + (n0 + r)) * 64 + tc] = f2bf(tile[tc][r]);
    }
}

// ------------------------------------------------------------------
// routing: one wave per (view, token). logits[e] = v.cw[e] - knorm[e]
// ------------------------------------------------------------------
__global__ __launch_bounds__(256) void route_kernel(
    const float* __restrict__ v0, const float* __restrict__ v1, const float* __restrict__ v2,
    const float* __restrict__ cw, const float* __restrict__ knorm,
    int* __restrict__ gidx, float* __restrict__ ggate, int* __restrict__ counts)
{
    __shared__ __align__(16) float cwS[N_EXP * D_MODEL];
    __shared__ float knS[N_EXP];
    int view = blockIdx.y;
    const float* src = view == 0 ? v0 : (view == 1 ? v1 : v2);
    for (int i = threadIdx.x; i < N_EXP * D_MODEL; i += 256)
        cwS[i] = cw[view * N_EXP * D_MODEL + i];
    if (threadIdx.x < N_EXP) knS[threadIdx.x] = knorm[threadIdx.x];
    __syncthreads();

    int wave = threadIdx.x >> 6, lane = threadIdx.x & 63;
    int token = blockIdx.x * 4 + wave;
    float4 v = ((const float4*)(src + (size_t)token * D_MODEL))[lane];

    float logits[N_EXP];
    #pragma unroll
    for (int e = 0; e < N_EXP; e++) {
        float4 w = *(const float4*)&cwS[e * D_MODEL + lane * 4];
        float p = v.x * w.x + v.y * w.y + v.z * w.z + v.w * w.w;
        #pragma unroll
        for (int s = 32; s > 0; s >>= 1) p += __shfl_xor(p, s, 64);
        logits[e] = p - knS[e];
    }
    int idxs[TOPK]; float vals[TOPK];
    #pragma unroll
    for (int k = 0; k < TOPK; k++) {
        float best = -1e30f; int bi = 0;
        #pragma unroll
        for (int e = 0; e < N_EXP; e++)
            if (logits[e] > best) { best = logits[e]; bi = e; }
        idxs[k] = bi; vals[k] = best;
        #pragma unroll
        for (int e = 0; e < N_EXP; e++)
            if (e == bi) logits[e] = -1e30f;
    }
    float m = vals[0], s = 0.f, ex[TOPK];
    #pragma unroll
    for (int k = 0; k < TOPK; k++) { ex[k] = expf(vals[k] - m); s += ex[k]; }
    float inv = 1.0f / s;
    if (lane < TOPK) {
        int k = lane;
        gidx [(view * N_TOK + token) * TOPK + k] = idxs[k];
        ggate[(view * N_TOK + token) * TOPK + k] = ex[k] * inv;
        atomicAdd(&counts[view * N_EXP + idxs[k]], 1);
    }
}

// ------------------------------------------------------------------
__global__ void scan_kernel(const int* __restrict__ counts, int* __restrict__ offs,
                            int* __restrict__ cursor) {
    if (threadIdx.x == 0) {
        int acc = 0;
        for (int g = 0; g < NGROUP; g++) { offs[g] = acc; cursor[g] = acc; acc += counts[g]; }
        offs[NGROUP] = acc;
    }
}

__global__ void fill_kernel(const int* __restrict__ gidx, const float* __restrict__ ggate,
                            int* __restrict__ cursor, int* __restrict__ rowTok,
                            float* __restrict__ rowGate) {
    int t = blockIdx.x * blockDim.x + threadIdx.x;
    if (t >= N_VIEWS * N_TOK) return;
    int view = t / N_TOK, token = t % N_TOK;
    #pragma unroll
    for (int k = 0; k < TOPK; k++) {
        int e = gidx[t * TOPK + k];
        float gg = ggate[t * TOPK + k];
        int pos = atomicAdd(&cursor[view * N_EXP + e], 1);
        rowTok[pos] = token;
        rowGate[pos] = gg;
    }
}

// ------------------------------------------------------------------
// fused expert FFN: one block = 128 rows of one (view, expert) group.
// X in A-frag registers; 16 chunks of 64 H-cols; GEMM1->gelu->LDS->GEMM2.
// ------------------------------------------------------------------
#define W1_STRIDE 264   // 256+8 (pad kills 16-way bank conflict)
#define W2_STRIDE 72    // 64+8
#define HC_STRIDE 72

__global__ __launch_bounds__(512) void ffn_kernel(
    const float* __restrict__ v0, const float* __restrict__ v1, const float* __restrict__ v2,
    const unsigned short* __restrict__ W1s, const unsigned short* __restrict__ W2s,
    const float* __restrict__ b1, const float* __restrict__ b2,
    const int* __restrict__ offs, const int* __restrict__ rowTok,
    const float* __restrict__ rowGate, float* __restrict__ out)
{
    __shared__ __align__(16) unsigned short Wc[256 * W2_STRIDE]; // 18432: fits W1 chunk (64x264) and W2 chunk (256x72)
    __shared__ __align__(16) unsigned short Hc[ROWS * HC_STRIDE];
    __shared__ int   tokS[ROWS];
    __shared__ float gateS[ROWS];

    int g = blockIdx.x;
    int view = g / N_EXP, e = g % N_EXP;
    int base = offs[g];
    int L = offs[g + 1] - base;
    int r0 = blockIdx.y * ROWS;
    if (r0 >= L) return;

    const float* src = view == 0 ? v0 : (view == 1 ? v1 : v2);
    int tid = threadIdx.x;
    if (tid < ROWS) {
        int gr = r0 + tid;
        int ok = gr < L;
        tokS[tid]  = ok ? rowTok[base + gr] : -1;
        gateS[tid] = ok ? rowGate[base + gr] : 0.f;
    }
    __syncthreads();

    int wave = tid >> 6, lane = tid & 63;
    int lmod = lane & 15, quad = lane >> 4;

    // X A-frags for GEMM1: wave handles rows [wave*16, wave*16+16)
    s16x8 areg[8];
    {
        int row = wave * 16 + lmod;
        int token = tokS[row];
        const float* vp = src + (size_t)(token < 0 ? 0 : token) * D_MODEL;
        #pragma unroll
        for (int ks = 0; ks < 8; ks++) {
            int k0 = ks * 32 + quad * 8;
            float f[8];
            if (token >= 0) {
                float4 a = *(const float4*)(vp + k0);
                float4 b = *(const float4*)(vp + k0 + 4);
                f[0]=a.x; f[1]=a.y; f[2]=a.z; f[3]=a.w; f[4]=b.x; f[5]=b.y; f[6]=b.z; f[7]=b.w;
            } else {
                #pragma unroll
                for (int j = 0; j < 8; j++) f[j] = 0.f;
            }
            s16x8 t;
            #pragma unroll
            for (int j = 0; j < 8; j++) t[j] = (short)f2bf(f[j]);
            areg[ks] = t;
        }
    }

    // persistent GEMM2 accumulators: wave -> rows (wave&1)*64, cols (wave>>1)*64
    f32x4 acc2[4][4];
    #pragma unroll
    for (int i = 0; i < 4; i++)
        #pragma unroll
        for (int j = 0; j < 4; j++) acc2[i][j] = (f32x4){0.f, 0.f, 0.f, 0.f};
    int rw0 = (wave & 1) * 64, cw0 = (wave >> 1) * 64;

    for (int c = 0; c < NCH; c++) {
        // ---- stage W1 chunk [n=64][k=256] -> Wc (stride 264)
        __syncthreads();
        {
            const unsigned short* gsrc = W1s + (size_t)(e * NCH + c) * (CH * D_MODEL);
            #pragma unroll
            for (int i = 0; i < 4; i++) {
                int idx8 = tid + i * 512;
                int n = idx8 >> 5, k = (idx8 & 31) * 8;
                s16x8 vv = *(const s16x8*)(gsrc + (size_t)idx8 * 8);
                *(s16x8*)&Wc[n * W1_STRIDE + k] = vv;
            }
        }
        __syncthreads();

        // ---- GEMM1: Hc[128][64] = X @ W1chunk, + b1, gelu
        f32x4 acc1[4];
        #pragma unroll
        for (int nt = 0; nt < 4; nt++) acc1[nt] = (f32x4){0.f, 0.f, 0.f, 0.f};
        #pragma unroll
        for (int ks = 0; ks < 8; ks++) {
            s16x8 a = areg[ks];
            #pragma unroll
            for (int nt = 0; nt < 4; nt++) {
                s16x8 b = *(const s16x8*)&Wc[(nt * 16 + lmod) * W1_STRIDE + ks * 32 + quad * 8];
                acc1[nt] = __builtin_amdgcn_mfma_f32_16x16x32_bf16(a, b, acc1[nt], 0, 0, 0);
            }
        }
        #pragma unroll
        for (int nt = 0; nt < 4; nt++) {
            float bb = b1[e * HDIM + c * CH + nt * 16 + lmod];
            #pragma unroll
            for (int r = 0; r < 4; r++) {
                float h = acc1[nt][r] + bb;
                float gl = 0.5f * h * (1.0f + erff(h * 0.70710678118f));  // exact gelu
                Hc[(wave * 16 + quad * 4 + r) * HC_STRIDE + nt * 16 + lmod] = f2bf(gl);
            }
        }
        __syncthreads();

        // ---- stage W2 chunk [n=256][kk=64] -> Wc (stride 72)
        {
            const unsigned short* gsrc = W2s + (size_t)(e * NCH + c) * (CH * D_MODEL);
            #pragma unroll
            for (int i = 0; i < 4; i++) {
                int idx8 = tid + i * 512;
                int n = idx8 >> 3, k = (idx8 & 7) * 8;
                s16x8 vv = *(const s16x8*)(gsrc + (size_t)idx8 * 8);
                *(s16x8*)&Wc[n * W2_STRIDE + k] = vv;
            }
        }
        __syncthreads();

        // ---- GEMM2: acc2 += Hc @ W2chunk
        #pragma unroll
        for (int ks = 0; ks < 2; ks++) {
            s16x8 afr[4];
            #pragma unroll
            for (int mt = 0; mt < 4; mt++)
                afr[mt] = *(const s16x8*)&Hc[(rw0 + mt * 16 + lmod) * HC_STRIDE + ks * 32 + quad * 8];
            #pragma unroll
            for (int nt = 0; nt < 4; nt++) {
                s16x8 b = *(const s16x8*)&Wc[(cw0 + nt * 16 + lmod) * W2_STRIDE + ks * 32 + quad * 8];
                #pragma unroll
                for (int mt = 0; mt < 4; mt++)
                    acc2[mt][nt] = __builtin_amdgcn_mfma_f32_16x16x32_bf16(afr[mt], b, acc2[mt][nt], 0, 0, 0);
            }
        }
    }

    // epilogue: out[token] += gate * (acc2 + b2)
    #pragma unroll
    for (int nt = 0; nt < 4; nt++) {
        int col = cw0 + nt * 16 + lmod;
        float b2v = b2[e * D_MODEL + col];
        #pragma unroll
        for (int mt = 0; mt < 4; mt++) {
            #pragma unroll
            for (int r = 0; r < 4; r++) {
                int rloc = rw0 + mt * 16 + quad * 4 + r;
                if (r0 + rloc < L) {
                    int token = tokS[rloc];
                    float gate = gateS[rloc];
                    atomicAdd(&out[(size_t)token * D_MODEL + col], gate * (acc2[mt][nt][r] + b2v));
                }
            }
        }
    }
}

// ------------------------------------------------------------------
extern "C" void kernel_launch(void* const* d_in, const int* in_sizes, int n_in,
                              void* d_out, int out_size, void* d_ws, size_t ws_size,
                              hipStream_t stream)
{
    const float* v0   = (const float*)d_in[0];
    const float* v1   = (const float*)d_in[1];
    const float* v2   = (const float*)d_in[2];
    const float* rw   = (const float*)d_in[3];
    const float* keys = (const float*)d_in[4];
    const float* W1   = (const float*)d_in[5];
    const float* b1   = (const float*)d_in[6];
    const float* W2   = (const float*)d_in[7];
    const float* b2   = (const float*)d_in[8];
    float* out = (float*)d_out;

    char* ws = (char*)d_ws;
    unsigned short* W1s = (unsigned short*)ws; ws += (size_t)N_EXP * HDIM * D_MODEL * 2; // 8 MB
    unsigned short* W2s = (unsigned short*)ws; ws += (size_t)N_EXP * HDIM * D_MODEL * 2; // 8 MB
    float* cw     = (float*)ws; ws += N_VIEWS * N_EXP * D_MODEL * 4;
    float* knorm  = (float*)ws; ws += 256;
    int*   counts = (int*)ws;   ws += 256;
    int*   offs   = (int*)ws;   ws += 256;
    int*   cursor = (int*)ws;   ws += 256;
    int*   gidx   = (int*)ws;   ws += N_VIEWS * N_TOK * TOPK * 4;
    float* ggate  = (float*)ws; ws += N_VIEWS * N_TOK * TOPK * 4;
    int*   rowTok = (int*)ws;   ws += N_VIEWS * N_TOK * TOPK * 4;
    float* rowGate= (float*)ws; ws += N_VIEWS * N_TOK * TOPK * 4;

    hipMemsetAsync(counts, 0, NGROUP * sizeof(int), stream);
    hipMemsetAsync(out, 0, (size_t)out_size * sizeof(float), stream);

    prep_kernel<<<1, 256, 0, stream>>>(rw, keys, cw, knorm);
    transpose_w1<<<dim3(16, 4, 16), 256, 0, stream>>>(W1, W1s);
    transpose_w2<<<dim3(4, 16, 16), 256, 0, stream>>>(W2, W2s);
    route_kernel<<<dim3(N_TOK / 4, N_VIEWS), 256, 0, stream>>>(v0, v1, v2, cw, knorm, gidx, ggate, counts);
    scan_kernel<<<1, 64, 0, stream>>>(counts, offs, cursor);
    fill_kernel<<<(N_VIEWS * N_TOK + 255) / 256, 256, 0, stream>>>(gidx, ggate, cursor, rowTok, rowGate);
    ffn_kernel<<<dim3(NGROUP, MAXTILE), 512, 0, stream>>>(v0, v1, v2, W1s, W2s, b1, b2,
                                                          offs, rowTok, rowGate, out);
}

// Round 2
// 472.999 us; speedup vs baseline: 1.8669x; 1.8669x over previous
//
#include <hip/hip_runtime.h>
#include <math.h>

#define D_MODEL 256
#define N_EXP   16
#define N_VIEWS 3
#define N_TOK   8192
#define TOPK    4
#define HDIM    1024
#define CH      64
#define NCH     16
#define ROWS    128
#define NGROUP  48
#define MAXTILE 64
#define CHUNK_ELTS (CH * D_MODEL)   // 16384 bf16 elements per staged W chunk (32 KB)

typedef short s16x8 __attribute__((ext_vector_type(8)));
typedef float f32x4 __attribute__((ext_vector_type(4)));

__device__ __forceinline__ unsigned short f2bf(float x) {
    union { float f; unsigned u; } a; a.f = x;
    unsigned r = a.u + 0x7FFFu + ((a.u >> 16) & 1u);   // RNE
    return (unsigned short)(r >> 16);
}

// ------------------------------------------------------------------
// views -> bf16, flat [view][token][d]
// ------------------------------------------------------------------
__global__ __launch_bounds__(256) void xbf_kernel(const float* __restrict__ v0,
                                                  const float* __restrict__ v1,
                                                  const float* __restrict__ v2,
                                                  unsigned short* __restrict__ Xbf) {
    int view = blockIdx.y;
    const float* src = view == 0 ? v0 : (view == 1 ? v1 : v2);
    size_t i4 = (size_t)blockIdx.x * blockDim.x + threadIdx.x;   // float4 index
    float4 v = ((const float4*)src)[i4];
    ushort4 o;
    o.x = f2bf(v.x); o.y = f2bf(v.y); o.z = f2bf(v.z); o.w = f2bf(v.w);
    ((ushort4*)(Xbf + (size_t)view * N_TOK * D_MODEL))[i4] = o;
}

// ------------------------------------------------------------------
// prep: cw[v][e][d] = 2*keys[e][d] + rw[v][e][d];  knorm[e] = ||k_e||^2
// ------------------------------------------------------------------
__global__ void prep_kernel(const float* __restrict__ rw, const float* __restrict__ keys,
                            float* __restrict__ cw, float* __restrict__ knorm) {
    int t = threadIdx.x;
    for (int i = t; i < N_VIEWS * N_EXP * D_MODEL; i += blockDim.x) {
        int ed = i % (N_EXP * D_MODEL);
        cw[i] = rw[i] + 2.0f * keys[ed];
    }
    if (t < N_EXP) {
        float s = 0.f;
        for (int d = 0; d < D_MODEL; d++) { float k = keys[t * D_MODEL + d]; s += k * k; }
        knorm[t] = s;
    }
}

// ------------------------------------------------------------------
// W1[e][k(256)][n(1024)] f32 -> W1f fragment order:
// [e][c(16)][ks(8)][ntile(4)][lane(64)][j(8)],
// element = W1[e][ks*32 + (lane>>4)*8 + j][c*64 + ntile*16 + (lane&15)]
// ------------------------------------------------------------------
__global__ __launch_bounds__(256) void w1frag_kernel(const float* __restrict__ W1,
                                                     unsigned short* __restrict__ W1f) {
    int c = blockIdx.x, e = blockIdx.y;
    const float* src = W1 + (size_t)e * 256 * 1024;
    unsigned short* dst = W1f + (size_t)(e * NCH + c) * CHUNK_ELTS;
    #pragma unroll
    for (int i = 0; i < 8; i++) {
        int idx = threadIdx.x + i * 256;          // 0..2047
        int lane = idx & 63, nt = (idx >> 6) & 3, ks = idx >> 8;
        int ncol = c * 64 + nt * 16 + (lane & 15);
        int kbase = ks * 32 + (lane >> 4) * 8;
        s16x8 o;
        #pragma unroll
        for (int j = 0; j < 8; j++) o[j] = (short)f2bf(src[(size_t)(kbase + j) * 1024 + ncol]);
        *(s16x8*)(dst + (size_t)idx * 8) = o;
    }
}

// ------------------------------------------------------------------
// W2[e][k2(1024)][n(256)] f32 -> W2f fragment order:
// [e][c(16)][ks2(2)][ntile(16)][lane(64)][j(8)],
// element = W2[e][c*64 + ks2*32 + (lane>>4)*8 + j][ntile*16 + (lane&15)]
// ------------------------------------------------------------------
__global__ __launch_bounds__(256) void w2frag_kernel(const float* __restrict__ W2,
                                                     unsigned short* __restrict__ W2f) {
    int c = blockIdx.x, e = blockIdx.y;
    const float* src = W2 + (size_t)e * 1024 * 256;
    unsigned short* dst = W2f + (size_t)(e * NCH + c) * CHUNK_ELTS;
    #pragma unroll
    for (int i = 0; i < 8; i++) {
        int idx = threadIdx.x + i * 256;          // 0..2047
        int lane = idx & 63, ntile = (idx >> 6) & 15, ks2 = idx >> 10;
        int n = ntile * 16 + (lane & 15);
        int kbase = c * 64 + ks2 * 32 + (lane >> 4) * 8;
        s16x8 o;
        #pragma unroll
        for (int j = 0; j < 8; j++) o[j] = (short)f2bf(src[(size_t)(kbase + j) * 256 + n]);
        *(s16x8*)(dst + (size_t)idx * 8) = o;
    }
}

// ------------------------------------------------------------------
// routing: block = 64 tokens (4 waves x 16 tokens), LDS-aggregated counts
// ------------------------------------------------------------------
__global__ __launch_bounds__(256) void route_kernel(
    const float* __restrict__ v0, const float* __restrict__ v1, const float* __restrict__ v2,
    const float* __restrict__ cw, const float* __restrict__ knorm,
    int* __restrict__ gidx, float* __restrict__ ggate, int* __restrict__ counts)
{
    __shared__ __align__(16) float cwS[N_EXP * D_MODEL];
    __shared__ float knS[N_EXP];
    __shared__ int lcnt[N_EXP];
    int view = blockIdx.y;
    const float* src = view == 0 ? v0 : (view == 1 ? v1 : v2);
    for (int i = threadIdx.x; i < N_EXP * D_MODEL; i += 256)
        cwS[i] = cw[view * N_EXP * D_MODEL + i];
    if (threadIdx.x < N_EXP) { knS[threadIdx.x] = knorm[threadIdx.x]; lcnt[threadIdx.x] = 0; }
    __syncthreads();

    int wave = threadIdx.x >> 6, lane = threadIdx.x & 63;
    for (int t = 0; t < 16; t++) {
        int token = blockIdx.x * 64 + wave * 16 + t;
        float4 v = ((const float4*)(src + (size_t)token * D_MODEL))[lane];
        float lg[N_EXP];
        #pragma unroll
        for (int e = 0; e < N_EXP; e++) {
            float4 w = *(const float4*)&cwS[e * D_MODEL + lane * 4];
            float p = v.x * w.x + v.y * w.y + v.z * w.z + v.w * w.w;
            #pragma unroll
            for (int s = 32; s > 0; s >>= 1) p += __shfl_xor(p, s, 64);
            lg[e] = p - knS[e];
        }
        int idxs[TOPK]; float vals[TOPK];
        #pragma unroll
        for (int k = 0; k < TOPK; k++) {
            float best = -1e30f; int bi = 0;
            #pragma unroll
            for (int e = 0; e < N_EXP; e++)
                if (lg[e] > best) { best = lg[e]; bi = e; }
            idxs[k] = bi; vals[k] = best;
            #pragma unroll
            for (int e = 0; e < N_EXP; e++)
                lg[e] = (e == bi) ? -1e30f : lg[e];
        }
        float m = vals[0], s = 0.f, ex[TOPK];
        #pragma unroll
        for (int k = 0; k < TOPK; k++) { ex[k] = __expf(vals[k] - m); s += ex[k]; }
        float inv = 1.0f / s;
        if (lane == 0) {
            size_t t4 = ((size_t)view * N_TOK + token) * TOPK;
            int4 gi; gi.x = idxs[0]; gi.y = idxs[1]; gi.z = idxs[2]; gi.w = idxs[3];
            *(int4*)&gidx[t4] = gi;
            float4 gv; gv.x = ex[0]*inv; gv.y = ex[1]*inv; gv.z = ex[2]*inv; gv.w = ex[3]*inv;
            *(float4*)&ggate[t4] = gv;
            atomicAdd(&lcnt[idxs[0]], 1); atomicAdd(&lcnt[idxs[1]], 1);
            atomicAdd(&lcnt[idxs[2]], 1); atomicAdd(&lcnt[idxs[3]], 1);
        }
    }
    __syncthreads();
    if (threadIdx.x < N_EXP && lcnt[threadIdx.x])
        atomicAdd(&counts[view * N_EXP + threadIdx.x], lcnt[threadIdx.x]);
}

// ------------------------------------------------------------------
__global__ void scan_kernel(const int* __restrict__ counts, int* __restrict__ offs,
                            int* __restrict__ cursor) {
    __shared__ int c[NGROUP];
    int t = threadIdx.x;
    if (t < NGROUP) c[t] = counts[t];
    __syncthreads();
    if (t <= NGROUP) {
        int acc = 0;
        for (int g = 0; g < t; g++) acc += c[g];
        if (t < NGROUP) { offs[t] = acc; cursor[t] = acc; }
        else offs[NGROUP] = acc;
    }
}

// ------------------------------------------------------------------
// fill: block = 256 tokens of one view; LDS-aggregated cursor claims
// ------------------------------------------------------------------
__global__ __launch_bounds__(256) void fill_kernel(const int* __restrict__ gidx,
                                                   const float* __restrict__ ggate,
                                                   int* __restrict__ cursor,
                                                   int* __restrict__ rowTok,
                                                   float* __restrict__ rowGate) {
    __shared__ int lc[N_EXP], lbase[N_EXP];
    int view = blockIdx.y;
    int token = blockIdx.x * 256 + threadIdx.x;
    if (threadIdx.x < N_EXP) lc[threadIdx.x] = 0;
    __syncthreads();
    size_t t4 = ((size_t)view * N_TOK + token) * TOPK;
    int4 e4 = *(const int4*)&gidx[t4];
    float4 g4 = *(const float4*)&ggate[t4];
    int e[4] = { e4.x, e4.y, e4.z, e4.w };
    float gg[4] = { g4.x, g4.y, g4.z, g4.w };
    int lp[4];
    #pragma unroll
    for (int k = 0; k < TOPK; k++) lp[k] = atomicAdd(&lc[e[k]], 1);
    __syncthreads();
    if (threadIdx.x < N_EXP)
        lbase[threadIdx.x] = lc[threadIdx.x] ? atomicAdd(&cursor[view * N_EXP + threadIdx.x], lc[threadIdx.x]) : 0;
    __syncthreads();
    #pragma unroll
    for (int k = 0; k < TOPK; k++) {
        int pos = lbase[e[k]] + lp[k];
        rowTok[pos] = token;
        rowGate[pos] = gg[k];
    }
}

// ------------------------------------------------------------------
// fused FFN: 1 block = 128 rows of one (view,expert) group; 512 thr, 8 waves.
// Conflict-free fragment-ordered LDS; 4 barriers/chunk; W prefetched into
// registers one phase ahead (VMEM latency hidden behind GEMMs).
// Registers ~220 -> 2 waves/SIMD, 1 block/CU (LDS 49 KB would allow more,
// but anything in 129..256 regs is the same occupancy; prefetch regs free).
// ------------------------------------------------------------------
__global__ __launch_bounds__(512, 2) void ffn_kernel(
    const unsigned short* __restrict__ Xbf,
    const unsigned short* __restrict__ W1f, const unsigned short* __restrict__ W2f,
    const float* __restrict__ b1, const float* __restrict__ b2,
    const int* __restrict__ offs, const int* __restrict__ rowTok,
    const float* __restrict__ rowGate, float* __restrict__ out)
{
    __shared__ __align__(16) unsigned short Wc[CHUNK_ELTS];   // 32 KB, W1/W2 alternately
    __shared__ __align__(16) unsigned short Hc[ROWS * CH];    // 16 KB, A-frag order
    __shared__ int   tokS[ROWS];
    __shared__ float gateS[ROWS];

    int g = blockIdx.x, view = g >> 4, e = g & 15;
    int base = offs[g];
    int L = offs[g + 1] - base;
    int r0 = blockIdx.y * ROWS;
    if (r0 >= L) return;

    int tid = threadIdx.x;
    if (tid < ROWS) {
        int gr = r0 + tid; bool ok = gr < L;
        tokS[tid]  = ok ? rowTok[base + gr] : -1;
        gateS[tid] = ok ? rowGate[base + gr] : 0.f;
    }

    const unsigned short* w1g = W1f + (size_t)e * NCH * CHUNK_ELTS;
    const unsigned short* w2g = W2f + (size_t)e * NCH * CHUNK_ELTS;

    // prologue prefetch: W1 chunk 0
    s16x8 t0, t1, t2, t3;
    {
        const s16x8* p = (const s16x8*)w1g + tid;
        t0 = p[0]; t1 = p[512]; t2 = p[1024]; t3 = p[1536];
    }
    __syncthreads();   // tokS ready

    int wave = tid >> 6, lane = tid & 63, lmod = lane & 15, quad = lane >> 4;
    int rg = wave >> 1, chf = wave & 1;    // GEMM1: rows rg*32, cols chf*32
    int rh = wave & 1, cs = wave >> 1;     // GEMM2: rows rh*64, cols cs*64

    // X A-fragments: 2 m-tiles per wave, held in registers (64 VGPR)
    s16x8 areg[2][8];
    #pragma unroll
    for (int mt2 = 0; mt2 < 2; mt2++) {
        int token = tokS[rg * 32 + mt2 * 16 + lmod];
        if (token < 0) token = 0;          // pad rows: garbage confined to their own rows
        const unsigned short* xp = Xbf + ((size_t)view * N_TOK + token) * D_MODEL;
        #pragma unroll
        for (int ks = 0; ks < 8; ks++)
            areg[mt2][ks] = *(const s16x8*)(xp + ks * 32 + quad * 8);
    }

    f32x4 acc2[4][4];
    #pragma unroll
    for (int i = 0; i < 4; i++)
        #pragma unroll
        for (int j = 0; j < 4; j++) acc2[i][j] = (f32x4){0.f, 0.f, 0.f, 0.f};

    for (int c = 0; c < NCH; c++) {
        __syncthreads();   // GEMM2[c-1] Wc/Hc reads complete
        {   // commit prefetched W1[c]
            s16x8* q = (s16x8*)Wc + tid;
            q[0] = t0; q[512] = t1; q[1024] = t2; q[1536] = t3;
        }
        __syncthreads();   // W1[c] visible
        {   // prefetch W2[c]
            const s16x8* p = (const s16x8*)(w2g + (size_t)c * CHUNK_ELTS) + tid;
            t0 = p[0]; t1 = p[512]; t2 = p[1024]; t3 = p[1536];
        }
        // ---- GEMM1: 32 rows x 32 cols per wave, K=256
        f32x4 acc1[2][2];
        #pragma unroll
        for (int i = 0; i < 2; i++)
            #pragma unroll
            for (int j = 0; j < 2; j++) acc1[i][j] = (f32x4){0.f, 0.f, 0.f, 0.f};
        #pragma unroll
        for (int ks = 0; ks < 8; ks++) {
            #pragma unroll
            for (int nt2 = 0; nt2 < 2; nt2++) {
                s16x8 b = *(const s16x8*)&Wc[((ks * 4 + chf * 2 + nt2) * 64 + lane) * 8];
                #pragma unroll
                for (int mt2 = 0; mt2 < 2; mt2++)
                    acc1[mt2][nt2] = __builtin_amdgcn_mfma_f32_16x16x32_bf16(
                        areg[mt2][ks], b, acc1[mt2][nt2], 0, 0, 0);
            }
        }
        // ---- bias + gelu (tanh approx) -> Hc in A-frag order
        #pragma unroll
        for (int nt2 = 0; nt2 < 2; nt2++) {
            int ntile = chf * 2 + nt2;
            float bb = b1[e * HDIM + c * CH + ntile * 16 + lmod];
            int qk = (nt2 << 1) | (lmod >> 3);
            #pragma unroll
            for (int mt2 = 0; mt2 < 2; mt2++) {
                int mtile = rg * 2 + mt2;
                int baseo = ((mtile * 2 + chf) * 64 + quad * 4 + 16 * qk) * 8 + (lmod & 7);
                #pragma unroll
                for (int r = 0; r < 4; r++) {
                    float h = acc1[mt2][nt2][r] + bb;
                    float u = h * (0.7978845608f + 0.0356774081f * h * h);
                    float ex2 = __expf(2.f * u);
                    float tn = 1.f - 2.f * __builtin_amdgcn_rcpf(1.f + ex2);
                    Hc[baseo + r * 8] = f2bf(0.5f * h * (1.f + tn));
                }
            }
        }
        __syncthreads();   // GEMM1 Wc reads + Hc writes complete
        {   // commit W2[c]
            s16x8* q = (s16x8*)Wc + tid;
            q[0] = t0; q[512] = t1; q[1024] = t2; q[1536] = t3;
        }
        __syncthreads();   // W2[c] + Hc visible
        if (c < NCH - 1) { // prefetch W1[c+1]
            const s16x8* p = (const s16x8*)(w1g + (size_t)(c + 1) * CHUNK_ELTS) + tid;
            t0 = p[0]; t1 = p[512]; t2 = p[1024]; t3 = p[1536];
        }
        // ---- GEMM2: 64x64 per wave, K=64 chunk
        #pragma unroll
        for (int ks2 = 0; ks2 < 2; ks2++) {
            s16x8 afr[4];
            #pragma unroll
            for (int mt = 0; mt < 4; mt++)
                afr[mt] = *(const s16x8*)&Hc[(((rh * 4 + mt) * 2 + ks2) * 64 + lane) * 8];
            #pragma unroll
            for (int nt = 0; nt < 4; nt++) {
                s16x8 b = *(const s16x8*)&Wc[((ks2 * 16 + cs * 4 + nt) * 64 + lane) * 8];
                #pragma unroll
                for (int mt = 0; mt < 4; mt++)
                    acc2[mt][nt] = __builtin_amdgcn_mfma_f32_16x16x32_bf16(
                        afr[mt], b, acc2[mt][nt], 0, 0, 0);
            }
        }
    }

    // epilogue: out[token] += gate * (acc2 + b2)
    #pragma unroll
    for (int nt = 0; nt < 4; nt++) {
        int col = (cs * 4 + nt) * 16 + lmod;
        float b2v = b2[e * D_MODEL + col];
        #pragma unroll
        for (int mt = 0; mt < 4; mt++) {
            #pragma unroll
            for (int r = 0; r < 4; r++) {
                int rloc = (rh * 4 + mt) * 16 + quad * 4 + r;
                if (r0 + rloc < L) {
                    atomicAdd(&out[(size_t)tokS[rloc] * D_MODEL + col],
                              gateS[rloc] * (acc2[mt][nt][r] + b2v));
                }
            }
        }
    }
}

// ------------------------------------------------------------------
extern "C" void kernel_launch(void* const* d_in, const int* in_sizes, int n_in,
                              void* d_out, int out_size, void* d_ws, size_t ws_size,
                              hipStream_t stream)
{
    const float* v0   = (const float*)d_in[0];
    const float* v1   = (const float*)d_in[1];
    const float* v2   = (const float*)d_in[2];
    const float* rw   = (const float*)d_in[3];
    const float* keys = (const float*)d_in[4];
    const float* W1   = (const float*)d_in[5];
    const float* b1   = (const float*)d_in[6];
    const float* W2   = (const float*)d_in[7];
    const float* b2   = (const float*)d_in[8];
    float* out = (float*)d_out;

    char* p = (char*)d_ws;
    unsigned short* Xbf = (unsigned short*)p; p += (size_t)N_VIEWS * N_TOK * D_MODEL * 2;
    unsigned short* W1f = (unsigned short*)p; p += (size_t)N_EXP * HDIM * D_MODEL * 2;
    unsigned short* W2f = (unsigned short*)p; p += (size_t)N_EXP * HDIM * D_MODEL * 2;
    float* cw     = (float*)p; p += N_VIEWS * N_EXP * D_MODEL * 4;
    float* knorm  = (float*)p; p += 256;
    int*   counts = (int*)p;   p += 256;
    int*   offs   = (int*)p;   p += 256;
    int*   cursor = (int*)p;   p += 256;
    int*   gidx   = (int*)p;   p += (size_t)N_VIEWS * N_TOK * TOPK * 4;
    float* ggate  = (float*)p; p += (size_t)N_VIEWS * N_TOK * TOPK * 4;
    int*   rowTok = (int*)p;   p += (size_t)N_VIEWS * N_TOK * TOPK * 4;
    float* rowGate= (float*)p; p += (size_t)N_VIEWS * N_TOK * TOPK * 4;

    hipMemsetAsync(counts, 0, NGROUP * sizeof(int), stream);
    hipMemsetAsync(out, 0, (size_t)out_size * sizeof(float), stream);

    xbf_kernel<<<dim3(N_TOK * D_MODEL / 4 / 256, N_VIEWS), 256, 0, stream>>>(v0, v1, v2, Xbf);
    prep_kernel<<<1, 256, 0, stream>>>(rw, keys, cw, knorm);
    w1frag_kernel<<<dim3(NCH, N_EXP), 256, 0, stream>>>(W1, W1f);
    w2frag_kernel<<<dim3(NCH, N_EXP), 256, 0, stream>>>(W2, W2f);
    route_kernel<<<dim3(N_TOK / 64, N_VIEWS), 256, 0, stream>>>(v0, v1, v2, cw, knorm,
                                                                gidx, ggate, counts);
    scan_kernel<<<1, 64, 0, stream>>>(counts, offs, cursor);
    fill_kernel<<<dim3(N_TOK / 256, N_VIEWS), 256, 0, stream>>>(gidx, ggate, cursor,
                                                                rowTok, rowGate);
    ffn_kernel<<<dim3(NGROUP, MAXTILE), 512, 0, stream>>>(Xbf, W1f, W2f, b1, b2,
                                                          offs, rowTok, rowGate, out);
}

// Round 3
// 466.687 us; speedup vs baseline: 1.8922x; 1.0135x over previous
//
#include <hip/hip_runtime.h>
#include <math.h>

#define D_MODEL 256
#define N_EXP   16
#define N_VIEWS 3
#define N_TOK   8192
#define TOPK    4
#define HDIM    1024
#define CH      64
#define NCH     16
#define ROWS    128
#define NGROUP  48
#define NTILES  816            // sum ceil(L_g/128) <= 768 + 48
#define REC_ELTS 32768         // one chunk record: W1 half (16384) + W2 half (16384) shorts

typedef short s16x8 __attribute__((ext_vector_type(8)));
typedef float f32x4 __attribute__((ext_vector_type(4)));

__device__ __forceinline__ unsigned short f2bf(float x) {
    union { float f; unsigned u; } a; a.f = x;
    unsigned r = a.u + 0x7FFFu + ((a.u >> 16) & 1u);   // RNE
    return (unsigned short)(r >> 16);
}

// async global -> LDS, 16 B per lane; ldst must be wave-uniform, lane offset implicit
__device__ __forceinline__ void dma16(const unsigned short* gp, unsigned short* lp) {
    __builtin_amdgcn_global_load_lds(
        (const __attribute__((address_space(1))) unsigned int*)gp,
        (__attribute__((address_space(3))) unsigned int*)lp, 16, 0, 0);
}

// stage one 32 KB half-record: 8 waves x 4 instr x 1 KB
__device__ __forceinline__ void dma_half(const unsigned short* gsrc, unsigned short* ldst,
                                         int wave, int lane) {
    #pragma unroll
    for (int i = 0; i < 4; i++) {
        int blk = wave * 4 + i;                       // 0..31, 1 KB blocks
        dma16(gsrc + ((size_t)blk * 64 + lane) * 8, ldst + blk * 512);
    }
}

// ------------------------------------------------------------------
// W1[e][k(256)][n(1024)] , W2[e][k2(1024)][n(256)] f32 -> combined frag records
// Wf[(e*NCH+c)*32768 + idx*8 + j]:
//   W1 half: idx=(ks*4+nt)*64+lane, elem = W1[e][ks*32+(lane>>4)*8+j][c*64+nt*16+(lane&15)]
//   W2 half: idx=(ks2*16+nt)*64+lane, elem = W2[e][c*64+ks2*32+(lane>>4)*8+j][nt*16+(lane&15)]
// ------------------------------------------------------------------
__global__ __launch_bounds__(256) void wfrag_kernel(const float* __restrict__ W1,
                                                    const float* __restrict__ W2,
                                                    unsigned short* __restrict__ Wf) {
    int c = blockIdx.x, e = blockIdx.y;
    unsigned short* dst = Wf + (size_t)(e * NCH + c) * REC_ELTS;
    if (blockIdx.z == 0) {
        const float* src = W1 + (size_t)e * 256 * 1024;
        #pragma unroll
        for (int i = 0; i < 8; i++) {
            int idx = threadIdx.x + i * 256;
            int lane = idx & 63, nt = (idx >> 6) & 3, ks = idx >> 8;
            int ncol = c * 64 + nt * 16 + (lane & 15);
            int kbase = ks * 32 + (lane >> 4) * 8;
            s16x8 o;
            #pragma unroll
            for (int j = 0; j < 8; j++) o[j] = (short)f2bf(src[(size_t)(kbase + j) * 1024 + ncol]);
            *(s16x8*)(dst + (size_t)idx * 8) = o;
        }
    } else {
        const float* src = W2 + (size_t)e * 1024 * 256;
        dst += 16384;
        #pragma unroll
        for (int i = 0; i < 8; i++) {
            int idx = threadIdx.x + i * 256;
            int lane = idx & 63, ntile = (idx >> 6) & 15, ks2 = idx >> 10;
            int n = ntile * 16 + (lane & 15);
            int kbase = c * 64 + ks2 * 32 + (lane >> 4) * 8;
            s16x8 o;
            #pragma unroll
            for (int j = 0; j < 8; j++) o[j] = (short)f2bf(src[(size_t)(kbase + j) * 256 + n]);
            *(s16x8*)(dst + (size_t)idx * 8) = o;
        }
    }
}

// ------------------------------------------------------------------
// routing (fused: cw/knorm build + bf16 X copy + logits + top4 + softmax)
// ------------------------------------------------------------------
__global__ __launch_bounds__(256) void route_kernel(
    const float* __restrict__ v0, const float* __restrict__ v1, const float* __restrict__ v2,
    const float* __restrict__ rw, const float* __restrict__ keys,
    unsigned short* __restrict__ Xbf,
    int* __restrict__ gidx, float* __restrict__ ggate, int* __restrict__ counts)
{
    __shared__ __align__(16) float cwS[N_EXP * D_MODEL];
    __shared__ float knS[N_EXP];
    __shared__ int lcnt[N_EXP];
    int view = blockIdx.y;
    const float* src = view == 0 ? v0 : (view == 1 ? v1 : v2);
    for (int i = threadIdx.x; i < N_EXP * D_MODEL; i += 256)
        cwS[i] = rw[view * N_EXP * D_MODEL + i] + 2.0f * keys[i];
    if (threadIdx.x < N_EXP) {
        const float4* kp = (const float4*)(keys + threadIdx.x * D_MODEL);
        float s = 0.f;
        for (int d = 0; d < 64; d++) { float4 k = kp[d]; s += k.x*k.x + k.y*k.y + k.z*k.z + k.w*k.w; }
        knS[threadIdx.x] = s; lcnt[threadIdx.x] = 0;
    }
    __syncthreads();

    int wave = threadIdx.x >> 6, lane = threadIdx.x & 63;
    for (int t = 0; t < 16; t++) {
        int token = blockIdx.x * 64 + wave * 16 + t;
        float4 v = ((const float4*)(src + (size_t)token * D_MODEL))[lane];
        ushort4 xo; xo.x = f2bf(v.x); xo.y = f2bf(v.y); xo.z = f2bf(v.z); xo.w = f2bf(v.w);
        ((ushort4*)(Xbf + ((size_t)view * N_TOK + token) * D_MODEL))[lane] = xo;
        float lg[N_EXP];
        #pragma unroll
        for (int e = 0; e < N_EXP; e++) {
            float4 w = *(const float4*)&cwS[e * D_MODEL + lane * 4];
            float p = v.x * w.x + v.y * w.y + v.z * w.z + v.w * w.w;
            #pragma unroll
            for (int s = 32; s > 0; s >>= 1) p += __shfl_xor(p, s, 64);
            lg[e] = p - knS[e];
        }
        int idxs[TOPK]; float vals[TOPK];
        #pragma unroll
        for (int k = 0; k < TOPK; k++) {
            float best = -1e30f; int bi = 0;
            #pragma unroll
            for (int e = 0; e < N_EXP; e++)
                if (lg[e] > best) { best = lg[e]; bi = e; }
            idxs[k] = bi; vals[k] = best;
            #pragma unroll
            for (int e = 0; e < N_EXP; e++)
                lg[e] = (e == bi) ? -1e30f : lg[e];
        }
        float m = vals[0], s = 0.f, ex[TOPK];
        #pragma unroll
        for (int k = 0; k < TOPK; k++) { ex[k] = __expf(vals[k] - m); s += ex[k]; }
        float inv = 1.0f / s;
        if (lane == 0) {
            size_t t4 = ((size_t)view * N_TOK + token) * TOPK;
            int4 gi; gi.x = idxs[0]; gi.y = idxs[1]; gi.z = idxs[2]; gi.w = idxs[3];
            *(int4*)&gidx[t4] = gi;
            float4 gv; gv.x = ex[0]*inv; gv.y = ex[1]*inv; gv.z = ex[2]*inv; gv.w = ex[3]*inv;
            *(float4*)&ggate[t4] = gv;
            atomicAdd(&lcnt[idxs[0]], 1); atomicAdd(&lcnt[idxs[1]], 1);
            atomicAdd(&lcnt[idxs[2]], 1); atomicAdd(&lcnt[idxs[3]], 1);
        }
    }
    __syncthreads();
    if (threadIdx.x < N_EXP && lcnt[threadIdx.x])
        atomicAdd(&counts[view * N_EXP + threadIdx.x], lcnt[threadIdx.x]);
}

// ------------------------------------------------------------------
// scan + compact tile list: tiles[s] = (g<<16)|tileIdx, -1 past the end
// ------------------------------------------------------------------
__global__ void scan_kernel(const int* __restrict__ counts, int* __restrict__ offs,
                            int* __restrict__ cursor, int* __restrict__ tiles) {
    __shared__ int cS[NGROUP + 1];
    int t = threadIdx.x;
    if (t == 0) {
        int acc = 0;
        for (int g = 0; g < NGROUP; g++) {
            offs[g] = acc; cursor[g] = acc; cS[g] = acc; acc += counts[g];
        }
        offs[NGROUP] = acc; cS[NGROUP] = acc;
    }
    __syncthreads();
    for (int s = t; s < NTILES; s += 256) {
        int rec = -1, cum = 0;
        for (int g = 0; g < NGROUP; g++) {
            int L = cS[g + 1] - cS[g];
            int nt = (L + ROWS - 1) / ROWS;
            if (s < cum + nt) { rec = (g << 16) | (s - cum); break; }
            cum += nt;
        }
        tiles[s] = rec;
    }
}

// ------------------------------------------------------------------
// fill: block = 256 tokens of one view; LDS-aggregated cursor claims
// ------------------------------------------------------------------
__global__ __launch_bounds__(256) void fill_kernel(const int* __restrict__ gidx,
                                                   const float* __restrict__ ggate,
                                                   int* __restrict__ cursor,
                                                   int* __restrict__ rowTok,
                                                   float* __restrict__ rowGate) {
    __shared__ int lc[N_EXP], lbase[N_EXP];
    int view = blockIdx.y;
    int token = blockIdx.x * 256 + threadIdx.x;
    if (threadIdx.x < N_EXP) lc[threadIdx.x] = 0;
    __syncthreads();
    size_t t4 = ((size_t)view * N_TOK + token) * TOPK;
    int4 e4 = *(const int4*)&gidx[t4];
    float4 g4 = *(const float4*)&ggate[t4];
    int e[4] = { e4.x, e4.y, e4.z, e4.w };
    float gg[4] = { g4.x, g4.y, g4.z, g4.w };
    int lp[4];
    #pragma unroll
    for (int k = 0; k < TOPK; k++) lp[k] = atomicAdd(&lc[e[k]], 1);
    __syncthreads();
    if (threadIdx.x < N_EXP)
        lbase[threadIdx.x] = lc[threadIdx.x] ? atomicAdd(&cursor[view * N_EXP + threadIdx.x], lc[threadIdx.x]) : 0;
    __syncthreads();
    #pragma unroll
    for (int k = 0; k < TOPK; k++) {
        int pos = lbase[e[k]] + lp[k];
        rowTok[pos] = token;
        rowGate[pos] = gg[k];
    }
}

// ------------------------------------------------------------------
// fused FFN: 1 block = 128 rows of one (view,expert) group; 512 thr, 8 waves.
// Single 64 KB W buffer (W1|W2 halves), async DMA staging one phase ahead,
// 2 barriers per chunk. Frag-ordered conflict-free LDS.
// ------------------------------------------------------------------
__global__ __launch_bounds__(512, 2) void ffn_kernel(
    const unsigned short* __restrict__ Xbf, const unsigned short* __restrict__ Wf,
    const float* __restrict__ b1, const float* __restrict__ b2,
    const int* __restrict__ offs, const int* __restrict__ tiles,
    const int* __restrict__ rowTok, const float* __restrict__ rowGate,
    float* __restrict__ out)
{
    __shared__ __align__(16) unsigned short Wbuf[REC_ELTS];   // 64 KB: [0,16384)=W1c, [16384,..)=W2c
    __shared__ __align__(16) unsigned short Hc[ROWS * CH];    // 16 KB, A-frag order
    __shared__ int   tokS[ROWS];
    __shared__ float gateS[ROWS];

    int rec = tiles[blockIdx.x];
    if (rec < 0) return;
    int g = rec >> 16, view = g >> 4, e = g & 15;
    int base = offs[g];
    int L = offs[g + 1] - base;
    int r0 = (rec & 0xffff) * ROWS;

    int tid = threadIdx.x;
    int wave = tid >> 6, lane = tid & 63, lmod = lane & 15, quad = lane >> 4;

    if (tid < ROWS) {
        int gr = r0 + tid; bool ok = gr < L;
        tokS[tid]  = ok ? rowTok[base + gr] : -1;
        gateS[tid] = ok ? rowGate[base + gr] : 0.f;
    }

    const unsigned short* wchunk = Wf + (size_t)e * NCH * REC_ELTS;
    // DMA W1[0]
    dma_half(wchunk, Wbuf, wave, lane);
    __syncthreads();            // tokS ready + W1[0] landed

    int rg = wave >> 1, chf = wave & 1;    // GEMM1: rows rg*32, cols chf*32
    int rh = wave & 1, cs = wave >> 1;     // GEMM2: rows rh*64, cols cs*64

    // X A-fragments: 2 m-tiles per wave (64 VGPR)
    s16x8 areg[2][8];
    #pragma unroll
    for (int mt2 = 0; mt2 < 2; mt2++) {
        int token = tokS[rg * 32 + mt2 * 16 + lmod];
        if (token < 0) token = 0;
        const unsigned short* xp = Xbf + ((size_t)view * N_TOK + token) * D_MODEL;
        #pragma unroll
        for (int ks = 0; ks < 8; ks++)
            areg[mt2][ks] = *(const s16x8*)(xp + ks * 32 + quad * 8);
    }
    // DMA W2[0] (lands during areg-loads + GEMM1[0])
    dma_half(wchunk + 16384, Wbuf + 16384, wave, lane);

    f32x4 acc2[4][4];
    #pragma unroll
    for (int i = 0; i < 4; i++)
        #pragma unroll
        for (int j = 0; j < 4; j++) acc2[i][j] = (f32x4){0.f, 0.f, 0.f, 0.f};

    for (int c = 0; c < NCH; c++) {
        // ---- GEMM1: 32x32 per wave, K=256, W1 half of Wbuf
        f32x4 acc1[2][2];
        #pragma unroll
        for (int i = 0; i < 2; i++)
            #pragma unroll
            for (int j = 0; j < 2; j++) acc1[i][j] = (f32x4){0.f, 0.f, 0.f, 0.f};
        #pragma unroll
        for (int ks = 0; ks < 8; ks++) {
            #pragma unroll
            for (int nt2 = 0; nt2 < 2; nt2++) {
                s16x8 b = *(const s16x8*)&Wbuf[((ks * 4 + chf * 2 + nt2) * 64 + lane) * 8];
                #pragma unroll
                for (int mt2 = 0; mt2 < 2; mt2++)
                    acc1[mt2][nt2] = __builtin_amdgcn_mfma_f32_16x16x32_bf16(
                        areg[mt2][ks], b, acc1[mt2][nt2], 0, 0, 0);
            }
        }
        // ---- bias + gelu -> Hc (A-frag order)
        #pragma unroll
        for (int nt2 = 0; nt2 < 2; nt2++) {
            int ntile = chf * 2 + nt2;
            float bb = b1[e * HDIM + c * CH + ntile * 16 + lmod];
            int qk = (nt2 << 1) | (lmod >> 3);
            #pragma unroll
            for (int mt2 = 0; mt2 < 2; mt2++) {
                int mtile = rg * 2 + mt2;
                int baseo = ((mtile * 2 + chf) * 64 + quad * 4 + 16 * qk) * 8 + (lmod & 7);
                #pragma unroll
                for (int r = 0; r < 4; r++) {
                    float h = acc1[mt2][nt2][r] + bb;
                    float u = h * (0.7978845608f + 0.0356774081f * h * h);
                    float ex2 = __expf(2.f * u);
                    float tn = 1.f - 2.f * __builtin_amdgcn_rcpf(1.f + ex2);
                    Hc[baseo + r * 8] = f2bf(0.5f * h * (1.f + tn));
                }
            }
        }
        __syncthreads();   // drains W2[c] DMA; Hc visible; GEMM1 done with W1 half
        if (c < NCH - 1)   // W1[c+1] -> W1 half (lands during GEMM2)
            dma_half(wchunk + (size_t)(c + 1) * REC_ELTS, Wbuf, wave, lane);
        // ---- GEMM2: 64x64 per wave, K=64, W2 half of Wbuf
        #pragma unroll
        for (int ks2 = 0; ks2 < 2; ks2++) {
            s16x8 afr[4];
            #pragma unroll
            for (int mt = 0; mt < 4; mt++)
                afr[mt] = *(const s16x8*)&Hc[(((rh * 4 + mt) * 2 + ks2) * 64 + lane) * 8];
            #pragma unroll
            for (int nt = 0; nt < 4; nt++) {
                s16x8 b = *(const s16x8*)&Wbuf[16384 + ((ks2 * 16 + cs * 4 + nt) * 64 + lane) * 8];
                #pragma unroll
                for (int mt = 0; mt < 4; mt++)
                    acc2[mt][nt] = __builtin_amdgcn_mfma_f32_16x16x32_bf16(
                        afr[mt], b, acc2[mt][nt], 0, 0, 0);
            }
        }
        __syncthreads();   // drains W1[c+1] DMA; GEMM2 done with W2 half + Hc
        if (c < NCH - 1)   // W2[c+1] -> W2 half (lands during GEMM1[c+1]+gelu)
            dma_half(wchunk + (size_t)(c + 1) * REC_ELTS + 16384, Wbuf + 16384, wave, lane);
    }

    // epilogue: out[token] += gate * (acc2 + b2)
    #pragma unroll
    for (int nt = 0; nt < 4; nt++) {
        int col = (cs * 4 + nt) * 16 + lmod;
        float b2v = b2[e * D_MODEL + col];
        #pragma unroll
        for (int mt = 0; mt < 4; mt++) {
            #pragma unroll
            for (int r = 0; r < 4; r++) {
                int rloc = (rh * 4 + mt) * 16 + quad * 4 + r;
                if (r0 + rloc < L) {
                    atomicAdd(&out[(size_t)tokS[rloc] * D_MODEL + col],
                              gateS[rloc] * (acc2[mt][nt][r] + b2v));
                }
            }
        }
    }
}

// ------------------------------------------------------------------
extern "C" void kernel_launch(void* const* d_in, const int* in_sizes, int n_in,
                              void* d_out, int out_size, void* d_ws, size_t ws_size,
                              hipStream_t stream)
{
    const float* v0   = (const float*)d_in[0];
    const float* v1   = (const float*)d_in[1];
    const float* v2   = (const float*)d_in[2];
    const float* rw   = (const float*)d_in[3];
    const float* keys = (const float*)d_in[4];
    const float* W1   = (const float*)d_in[5];
    const float* b1   = (const float*)d_in[6];
    const float* W2   = (const float*)d_in[7];
    const float* b2   = (const float*)d_in[8];
    float* out = (float*)d_out;

    char* p = (char*)d_ws;
    unsigned short* Xbf = (unsigned short*)p; p += (size_t)N_VIEWS * N_TOK * D_MODEL * 2;
    unsigned short* Wf  = (unsigned short*)p; p += (size_t)N_EXP * NCH * REC_ELTS * 2;
    int*   counts = (int*)p;   p += 256;
    int*   offs   = (int*)p;   p += 256;
    int*   cursor = (int*)p;   p += 256;
    int*   tiles  = (int*)p;   p += NTILES * 4 + 64;
    int*   gidx   = (int*)p;   p += (size_t)N_VIEWS * N_TOK * TOPK * 4;
    float* ggate  = (float*)p; p += (size_t)N_VIEWS * N_TOK * TOPK * 4;
    int*   rowTok = (int*)p;   p += (size_t)N_VIEWS * N_TOK * TOPK * 4;
    float* rowGate= (float*)p; p += (size_t)N_VIEWS * N_TOK * TOPK * 4;

    hipMemsetAsync(counts, 0, NGROUP * sizeof(int), stream);
    hipMemsetAsync(out, 0, (size_t)out_size * sizeof(float), stream);

    wfrag_kernel<<<dim3(NCH, N_EXP, 2), 256, 0, stream>>>(W1, W2, Wf);
    route_kernel<<<dim3(N_TOK / 64, N_VIEWS), 256, 0, stream>>>(v0, v1, v2, rw, keys, Xbf,
                                                                gidx, ggate, counts);
    scan_kernel<<<1, 256, 0, stream>>>(counts, offs, cursor, tiles);
    fill_kernel<<<dim3(N_TOK / 256, N_VIEWS), 256, 0, stream>>>(gidx, ggate, cursor,
                                                                rowTok, rowGate);
    ffn_kernel<<<dim3(NTILES), 512, 0, stream>>>(Xbf, Wf, b1, b2, offs, tiles,
                                                 rowTok, rowGate, out);
}